// Round 11
// baseline (156.536 us; speedup 1.0000x reference)
//
#include <hip/hip_runtime.h>

// ConvTranspose3d (2,64,32^3) fp32 -> (2,32,66^3), stride2 pad1 outpad1 dil2 k3.
// Odd-grid MFMA: out[n,co,2dp+1,2hp+1,2wp+1] = bias[co] +
//   sum_{ci,kd,kh,kw} x[n,ci,dp+1-kd,hp+1-kh,wp+1-kw] * w[ci,co,kd,kh,kw]
// R24 = R18 (best, 102.7) with the wprep LAUNCH removed (last untested
// lever: launch count; R22 measured +1 launch ~ +10us).
//  - block 0 packs wA (f32 w -> f16, 216x256 values, ~2-3us) BEFORE its
//    staging, then publishes: per-thread __threadfence -> __syncthreads ->
//    tid0 atomicExch(flag, MAGIC)  (device-scope, Guideline 16 pattern).
//  - blocks!=0: stage first (no wA dependency), then tid0 relaxed-spins on
//    flag (s_sleep between polls; no cache-wide invalidates while polling),
//    one acquire load, then B1; all threads __threadfence() after B1 so
//    the wA reads (cc-loop) see fresh data across XCDs.
//  - Deadlock-free: block 0 never waits before signaling; any non-resident
//    block starts later and finds the flag set.
//  - Replay-safe: wA is iteration-invariant; a stale MAGIC flag only lets
//    consumers read concurrently-rewritten IDENTICAL bits.
// Everything else (decode, staging, MFMA, C-D map, store order) verbatim R18.

#define DOUT 66
#define PL (DOUT*DOUT)                  // 4356 floats/plane
#define ROW_B 4352                      // bytes per (id,ih) LDS row
#define IDG_B (6*ROW_B)                 // 6 ih-rows per id group = 26112 B
#define FLAG_OFF 110592                 // flag right after wA
#define MAGIC 0x1F2E3D4Cu

typedef _Float16 half8   __attribute__((ext_vector_type(8)));
typedef float    floatx16 __attribute__((ext_vector_type(16)));
typedef float    floatx4  __attribute__((ext_vector_type(4)));

// ---- fused: w-pack (block 0) + repack + conv, 4 hp tiles (1/wave) ----
__global__ void __launch_bounds__(256, 2) convt(
    const float* __restrict__ x, const float* __restrict__ w,
    const float* __restrict__ bias, float* __restrict__ out,
    _Float16* __restrict__ wA, unsigned* __restrict__ flag)
{
    __shared__ __align__(16) unsigned char xlds[3 * IDG_B];   // 78336 B

    const int tid  = threadIdx.x;
    const int lane = tid & 63;
    const int wv   = tid >> 6;           // wave = hp tile index

    unsigned b = blockIdx.x;             // 512: xcd(3) | hsub(1) | dp(5)  [R18]
    const unsigned xcd = b & 7u;
    const int n     = (int)(xcd & 1u);
    const unsigned rest = b >> 3;
    const int hpg   = (int)((xcd >> 1) * 2 + (rest & 1u));   // 0..7
    const int dp    = (int)(rest >> 1);                      // 0..31
    const int hpb   = hpg * 4;           // hp = hpb..hpb+3

    const float* xn = x + (size_t)n * 2097152;

    // store-role indices (R18 form)
    const int co_s = tid >> 3;           // 0..31
    const int l8   = tid & 7;
    const float bvc = bias[co_s];
    const floatx4 bb4 = {bvc, bvc, bvc, bvc};

    // ---- block 0: w-pack then publish (before its own staging) ----
    if (b == 0) {
        for (int it = 0; it < 216; ++it) {
            const int o = it * 256 + tid;            // < 55296
            const int j = o & 7;
            const int tmp = o >> 3;
            const int ln = tmp & 63;
            const int g = tmp >> 6;
            const int cc = g / 27, tap = g - cc * 27;
            const int co = ln & 31, kh = ln >> 5;
            const int ci = cc * 16 + kh * 8 + j;
            wA[o] = (_Float16)w[ci * 864 + co * 27 + tap];
        }
        __threadfence();                 // write-back this thread's wA stores
        __syncthreads();                 // all 256 threads fenced
        if (tid == 0) atomicExch(flag, MAGIC);       // device-scope publish
    }

    // ---- staging: 18 rows (id 3 x ih 6), 1152 tasks, wave-uniform rows ----
    {
        for (int t = tid; t < 1152; t += 256) {
            const int r   = t >> 6;
            const int ccg = (t >> 3) & 7;
            const int gq  = t & 7;
            const int id_l = r / 6, ihl = r - 6 * id_l;
            const int id = dp - 1 + id_l;
            const int ih = hpb - 1 + ihl;
            unsigned char* dst = xlds + (id_l * 6 + ihl) * ROW_B
                               + ccg * 544 + (gq * 4 + 1) * 16;
            if (((unsigned)id < 32u) & ((unsigned)ih < 32u)) {
                const float* src = xn + ccg * 262144 + (id * 32 + ih) * 32 + gq * 4;
                floatx4 f[8];
                #pragma unroll
                for (int j = 0; j < 8; ++j) f[j] = *(const floatx4*)(src + j * 32768);
                #pragma unroll
                for (int m = 0; m < 4; ++m) {
                    unsigned p0 = __builtin_bit_cast(unsigned,
                        __builtin_amdgcn_cvt_pkrtz(f[0][m], f[1][m]));
                    unsigned p1 = __builtin_bit_cast(unsigned,
                        __builtin_amdgcn_cvt_pkrtz(f[2][m], f[3][m]));
                    unsigned p2 = __builtin_bit_cast(unsigned,
                        __builtin_amdgcn_cvt_pkrtz(f[4][m], f[5][m]));
                    unsigned p3 = __builtin_bit_cast(unsigned,
                        __builtin_amdgcn_cvt_pkrtz(f[6][m], f[7][m]));
                    *(uint4*)(dst + m * 16) = make_uint4(p0, p1, p2, p3);
                }
            } else {
                #pragma unroll
                for (int m = 0; m < 4; ++m)
                    *(uint4*)(dst + m * 16) = make_uint4(0, 0, 0, 0);
            }
        }
        // halo iwl 0/33: 18 rows x 8 ccg x 2 sides = 288 cells
        for (int h = tid; h < 288; h += 256) {
            const int r = h >> 4, rem = h & 15;
            const int cg = rem >> 1, side = rem & 1;
            *(uint4*)(xlds + r * ROW_B + cg * 544 + (side ? 33 * 16 : 0)) =
                make_uint4(0, 0, 0, 0);
        }
    }

    // ---- wait for wA (blocks != 0): relaxed poll, then acquire ----
    if (b != 0 && tid == 0) {
        while (__hip_atomic_load(flag, __ATOMIC_RELAXED,
                                 __HIP_MEMORY_SCOPE_AGENT) != MAGIC)
            __builtin_amdgcn_s_sleep(2);
        (void)__hip_atomic_load(flag, __ATOMIC_ACQUIRE,
                                __HIP_MEMORY_SCOPE_AGENT);
    }
    __syncthreads();                                 // B1: LDS staged + wA ready
    if (b != 0) __threadfence();                     // invalidate stale wA lines

    // ---- MFMA: wave wv owns hp = hpb+wv; loop all 4 ci chunks ----
    const int wp    = lane & 31;
    const int khalf = lane >> 5;

    floatx16 acc = {};
    #pragma unroll
    for (int cc = 0; cc < 4; ++cc) {
        uint4 A[27];
        const _Float16* wl = wA + ((size_t)cc * 27 * 64 + lane) * 8;
        #pragma unroll
        for (int t = 0; t < 27; ++t) A[t] = *(const uint4*)(wl + t * 512);
        const int cb = (2 * cc + khalf) * 544 + wp * 16;
        #pragma unroll
        for (int kd = 0; kd < 3; ++kd)
        #pragma unroll
        for (int kh = 0; kh < 3; ++kh)
        #pragma unroll
        for (int kw = 0; kw < 3; ++kw) {
            const int tap = (kd * 3 + kh) * 3 + kw;
            const uint4* bp = (const uint4*)(xlds
                + ((2 - kd) * 6 + (wv + 2 - kh)) * ROW_B + cb + (2 - kw) * 16);
            acc = __builtin_amdgcn_mfma_f32_32x32x16_f16(
                __builtin_bit_cast(half8, A[tap]),
                __builtin_bit_cast(half8, bp[0]), acc, 0, 0, 0);
        }
    }

    // ---- vals to LDS: val[hp_local 4][co 32][wp 32 +pad] ----
    __syncthreads();                                 // B2: MFMA reads done
    float* val = (float*)xlds;                       // 4*32*33*4 = 16896 B
    #pragma unroll
    for (int r = 0; r < 16; ++r) {
        const int co = (r & 3) + 8 * (r >> 2) + 4 * khalf;   // verified C/D map
        val[((size_t)wv * 32 + co) * 33 + wp] = acc[r];
    }
    __syncthreads();                                 // B3: vals visible

    // ======== ALL global stores below this line (drain only at endpgm) ====

    // ---- odd-plane span store: 8 rows (2112 B) per co, values interleaved ----
    {
        float* base = out + ((size_t)(n * 32 + co_s) * DOUT + 2 * dp + 1) * PL
                      + 8 * hpg * DOUT;
        #pragma unroll
        for (int p = 0; p < 17; ++p) {
            const int q = l8 + 8 * p;
            if (q < 132) {
                floatx4 o;
                #pragma unroll
                for (int j = 0; j < 4; ++j) {
                    const int e = 4 * q + j;          // 0..527
                    const int rl = e / 66;            // span row 0..7
                    const int ow = e - rl * 66;
                    float v = bvc;
                    if ((rl & 1) && (ow & 1) && ow < 65)
                        v += val[(((rl >> 1) * 32) + co_s) * 33 + (ow >> 1)];
                    o[j] = v;
                }
                *(floatx4*)(base + 4 * q) = o;
            }
        }
        if (hpg == 7) {                               // tail rows 64,65: bias only
            for (int p = 0; p < 5; ++p) {
                const int q = 132 + l8 + 8 * p;
                if (q < 165) *(floatx4*)(base + 4 * q) = bb4;
            }
        }
    }

    // ---- even-plane bias span (+ planes 64/65 at dp31) ----
    {
        const int nq = (hpg == 7) ? 165 : 132;       // float4s in span
        float* eb = out + ((size_t)(n * 32 + co_s) * DOUT + 2 * dp) * PL
                    + 8 * hpg * DOUT;
        for (int q = l8; q < nq; q += 8) *(floatx4*)(eb + 4 * q) = bb4;
        if (dp == 31) {
            float* p64 = out + ((size_t)(n * 32 + co_s) * DOUT + 64) * PL
                         + 8 * hpg * DOUT;
            for (int q = l8; q < nq; q += 8) *(floatx4*)(p64 + 4 * q) = bb4;
            float* p65 = p64 + PL;
            for (int q = l8; q < nq; q += 8) *(floatx4*)(p65 + 4 * q) = bb4;
        }
    }
}

extern "C" void kernel_launch(void* const* d_in, const int* in_sizes, int n_in,
                              void* d_out, int out_size, void* d_ws, size_t ws_size,
                              hipStream_t stream) {
    const float* x    = (const float*)d_in[0];
    const float* wgt  = (const float*)d_in[1];
    const float* bias = (const float*)d_in[2];
    float* out = (float*)d_out;
    _Float16* wA   = (_Float16*)d_ws;                    // 110592 B
    unsigned* flag = (unsigned*)((char*)d_ws + FLAG_OFF);

    convt<<<512, 256, 0, stream>>>(x, wgt, bias, out, wA, flag);
}

// Round 12
// 102.970 us; speedup vs baseline: 1.5202x; 1.5202x over previous
//
#include <hip/hip_runtime.h>

// ConvTranspose3d (2,64,32^3) fp32 -> (2,32,66^3), stride2 pad1 outpad1 dil2 k3.
// Odd-grid MFMA: out[n,co,2dp+1,2hp+1,2wp+1] = bias[co] +
//   sum_{ci,kd,kh,kw} x[n,ci,dp+1-kd,hp+1-kh,wp+1-kw] * w[ci,co,kd,kh,kw]
// R25 = R18 restored verbatim (session optimum, 102.7 us).
// Final configuration after 11 rounds of A/B:
//  - fused repack: x fp32 -> f16 LDS tiles in-kernel (no x16 HBM round trip)
//  - 4 hp tiles per block, one wave each, no split-K (each wave loops all
//    4 ci chunks; A[27] reloads are L2-hot)
//  - strict phase order: ALL global loads -> compute -> ALL global stores;
//    plain __syncthreads only; no store issued before any barrier
//    (vmcnt is an in-order FIFO: pre-barrier stores poison load waits)
//  - store spans: 8-row (2112 B) contiguous runs per co, float4 lanes
//  - losers (measured): rolling-dp pipeline (null), wave-contig 1KB stores
//    (+8), bias-first / LDS-only barriers (+8), post-load bias overlap (+7),
//    compact+expand split (+10), XCD write remap (+6.6), single-launch
//    w-pack fusion (+54, serialized behind block 0).

#define DOUT 66
#define PL (DOUT*DOUT)                  // 4356 floats/plane
#define ROW_B 4352                      // bytes per (id,ih) LDS row
#define IDG_B (6*ROW_B)                 // 6 ih-rows per id group = 26112 B

typedef _Float16 half8   __attribute__((ext_vector_type(8)));
typedef float    floatx16 __attribute__((ext_vector_type(16)));
typedef float    floatx4  __attribute__((ext_vector_type(4)));

// ---- k1: w-pack. wA[cc 4][tap 27][lane 64][8 f16]; lane=co+32*khalf ----
__global__ void __launch_bounds__(256) wprep(const float* __restrict__ w,
                                             _Float16* __restrict__ wA)
{
    int o = blockIdx.x * 256 + threadIdx.x;   // < 55296 = 216*256
    int j = o & 7;
    int tmp = o >> 3;
    int lane = tmp & 63;
    int g = tmp >> 6;
    int cc = g / 27, tap = g - cc * 27;
    int co = lane & 31, khalf = lane >> 5;
    int ci = cc * 16 + khalf * 8 + j;
    wA[o] = (_Float16)w[ci * 864 + co * 27 + tap];
}

// ---- k2: fused repack + conv, 4 hp tiles (1/wave), stores after barriers ----
__global__ void __launch_bounds__(256, 2) convt(
    const float* __restrict__ x, const _Float16* __restrict__ wA,
    const float* __restrict__ bias, float* __restrict__ out)
{
    __shared__ __align__(16) unsigned char xlds[3 * IDG_B];   // 78336 B

    const int tid  = threadIdx.x;
    const int lane = tid & 63;
    const int wv   = tid >> 6;           // wave = hp tile index

    unsigned b = blockIdx.x;             // 512: xcd(3) | hsub(1) | dp(5)
    const unsigned xcd = b & 7u;
    const int n     = (int)(xcd & 1u);
    const unsigned rest = b >> 3;
    const int hpg   = (int)((xcd >> 1) * 2 + (rest & 1u));   // 0..7
    const int dp    = (int)(rest >> 1);                      // 0..31
    const int hpb   = hpg * 4;           // hp = hpb..hpb+3

    const float* xn = x + (size_t)n * 2097152;

    // store-role indices
    const int co_s = tid >> 3;           // 0..31
    const int l8   = tid & 7;
    const float bvc = bias[co_s];
    const floatx4 bb4 = {bvc, bvc, bvc, bvc};

    // ---- staging: 18 rows (id 3 x ih 6), 1152 tasks, wave-uniform rows ----
    {
        for (int t = tid; t < 1152; t += 256) {
            const int r   = t >> 6;
            const int ccg = (t >> 3) & 7;
            const int gq  = t & 7;
            const int id_l = r / 6, ihl = r - 6 * id_l;
            const int id = dp - 1 + id_l;
            const int ih = hpb - 1 + ihl;
            unsigned char* dst = xlds + (id_l * 6 + ihl) * ROW_B
                               + ccg * 544 + (gq * 4 + 1) * 16;
            if (((unsigned)id < 32u) & ((unsigned)ih < 32u)) {
                const float* src = xn + ccg * 262144 + (id * 32 + ih) * 32 + gq * 4;
                floatx4 f[8];
                #pragma unroll
                for (int j = 0; j < 8; ++j) f[j] = *(const floatx4*)(src + j * 32768);
                #pragma unroll
                for (int m = 0; m < 4; ++m) {
                    unsigned p0 = __builtin_bit_cast(unsigned,
                        __builtin_amdgcn_cvt_pkrtz(f[0][m], f[1][m]));
                    unsigned p1 = __builtin_bit_cast(unsigned,
                        __builtin_amdgcn_cvt_pkrtz(f[2][m], f[3][m]));
                    unsigned p2 = __builtin_bit_cast(unsigned,
                        __builtin_amdgcn_cvt_pkrtz(f[4][m], f[5][m]));
                    unsigned p3 = __builtin_bit_cast(unsigned,
                        __builtin_amdgcn_cvt_pkrtz(f[6][m], f[7][m]));
                    *(uint4*)(dst + m * 16) = make_uint4(p0, p1, p2, p3);
                }
            } else {
                #pragma unroll
                for (int m = 0; m < 4; ++m)
                    *(uint4*)(dst + m * 16) = make_uint4(0, 0, 0, 0);
            }
        }
        // halo iwl 0/33: 18 rows x 8 ccg x 2 sides = 288 cells
        for (int h = tid; h < 288; h += 256) {
            const int r = h >> 4, rem = h & 15;
            const int cg = rem >> 1, side = rem & 1;
            *(uint4*)(xlds + r * ROW_B + cg * 544 + (side ? 33 * 16 : 0)) =
                make_uint4(0, 0, 0, 0);
        }
    }
    __syncthreads();                                 // B1: LDS staged (loads only)

    // ---- MFMA: wave wv owns hp = hpb+wv; loop all 4 ci chunks ----
    const int wp    = lane & 31;
    const int khalf = lane >> 5;

    floatx16 acc = {};
    #pragma unroll
    for (int cc = 0; cc < 4; ++cc) {
        uint4 A[27];
        const _Float16* wl = wA + ((size_t)cc * 27 * 64 + lane) * 8;
        #pragma unroll
        for (int t = 0; t < 27; ++t) A[t] = *(const uint4*)(wl + t * 512);
        const int cb = (2 * cc + khalf) * 544 + wp * 16;
        #pragma unroll
        for (int kd = 0; kd < 3; ++kd)
        #pragma unroll
        for (int kh = 0; kh < 3; ++kh)
        #pragma unroll
        for (int kw = 0; kw < 3; ++kw) {
            const int tap = (kd * 3 + kh) * 3 + kw;
            const uint4* bp = (const uint4*)(xlds
                + ((2 - kd) * 6 + (wv + 2 - kh)) * ROW_B + cb + (2 - kw) * 16);
            acc = __builtin_amdgcn_mfma_f32_32x32x16_f16(
                __builtin_bit_cast(half8, A[tap]),
                __builtin_bit_cast(half8, bp[0]), acc, 0, 0, 0);
        }
    }

    // ---- vals to LDS: val[hp_local 4][co 32][wp 32 +pad] ----
    __syncthreads();                                 // B2: MFMA reads done
    float* val = (float*)xlds;                       // 4*32*33*4 = 16896 B
    #pragma unroll
    for (int r = 0; r < 16; ++r) {
        const int co = (r & 3) + 8 * (r >> 2) + 4 * khalf;   // verified C/D map
        val[((size_t)wv * 32 + co) * 33 + wp] = acc[r];
    }
    __syncthreads();                                 // B3: vals visible

    // ======== ALL global stores below this line (drain only at endpgm) ====

    // ---- odd-plane span store: 8 rows (2112 B) per co, values interleaved ----
    {
        float* base = out + ((size_t)(n * 32 + co_s) * DOUT + 2 * dp + 1) * PL
                      + 8 * hpg * DOUT;
        #pragma unroll
        for (int p = 0; p < 17; ++p) {
            const int q = l8 + 8 * p;
            if (q < 132) {
                floatx4 o;
                #pragma unroll
                for (int j = 0; j < 4; ++j) {
                    const int e = 4 * q + j;          // 0..527
                    const int rl = e / 66;            // span row 0..7
                    const int ow = e - rl * 66;
                    float v = bvc;
                    if ((rl & 1) && (ow & 1) && ow < 65)
                        v += val[(((rl >> 1) * 32) + co_s) * 33 + (ow >> 1)];
                    o[j] = v;
                }
                *(floatx4*)(base + 4 * q) = o;
            }
        }
        if (hpg == 7) {                               // tail rows 64,65: bias only
            for (int p = 0; p < 5; ++p) {
                const int q = 132 + l8 + 8 * p;
                if (q < 165) *(floatx4*)(base + 4 * q) = bb4;
            }
        }
    }

    // ---- even-plane bias span (+ planes 64/65 at dp31) ----
    {
        const int nq = (hpg == 7) ? 165 : 132;       // float4s in span
        float* eb = out + ((size_t)(n * 32 + co_s) * DOUT + 2 * dp) * PL
                    + 8 * hpg * DOUT;
        for (int q = l8; q < nq; q += 8) *(floatx4*)(eb + 4 * q) = bb4;
        if (dp == 31) {
            float* p64 = out + ((size_t)(n * 32 + co_s) * DOUT + 64) * PL
                         + 8 * hpg * DOUT;
            for (int q = l8; q < nq; q += 8) *(floatx4*)(p64 + 4 * q) = bb4;
            float* p65 = p64 + PL;
            for (int q = l8; q < nq; q += 8) *(floatx4*)(p65 + 4 * q) = bb4;
        }
    }
}

extern "C" void kernel_launch(void* const* d_in, const int* in_sizes, int n_in,
                              void* d_out, int out_size, void* d_ws, size_t ws_size,
                              hipStream_t stream) {
    const float* x    = (const float*)d_in[0];
    const float* wgt  = (const float*)d_in[1];
    const float* bias = (const float*)d_in[2];
    float* out = (float*)d_out;
    _Float16* wA = (_Float16*)d_ws;      // 110592 B

    wprep<<<216, 256, 0, stream>>>(wgt, wA);
    convt<<<512, 256, 0, stream>>>(x, wA, bias, out);
}